// Round 6
// baseline (1648.212 us; speedup 1.0000x reference)
//
#include <hip/hip_runtime.h>
#include <stdint.h>
#include <stddef.h>

typedef _Float16 half_t;
typedef _Float16 half2_t __attribute__((ext_vector_type(2)));
typedef _Float16 half8_t __attribute__((ext_vector_type(8)));
typedef float    floatx4 __attribute__((ext_vector_type(4)));
typedef uint32_t u32x4   __attribute__((ext_vector_type(4)));

#define SEQ_L 512
#define NBATCH 64
#define DIM 256
#define NTOT (NBATCH * SEQ_L)   // 32768 rows

// ---------- helpers ----------
__device__ __forceinline__ float fdot2f(uint32_t a, uint32_t b, float c) {
#if defined(__has_builtin)
#if __has_builtin(__builtin_amdgcn_fdot2)
  return __builtin_amdgcn_fdot2(__builtin_bit_cast(half2_t, a),
                                __builtin_bit_cast(half2_t, b), c, false);
#else
  half2_t av = __builtin_bit_cast(half2_t, a);
  half2_t bv = __builtin_bit_cast(half2_t, b);
  return c + (float)av[0] * (float)bv[0] + (float)av[1] * (float)bv[1];
#endif
#else
  half2_t av = __builtin_bit_cast(half2_t, a);
  half2_t bv = __builtin_bit_cast(half2_t, b);
  return c + (float)av[0] * (float)bv[0] + (float)av[1] * (float)bv[1];
#endif
}

__device__ __forceinline__ float sigmoidf_fast(float x) {
  return 1.0f / (1.0f + __expf(-x));
}
__device__ __forceinline__ float tanhf_fast(float x) {
  float e = __expf(2.0f * x);
  return 1.0f - 2.0f / (e + 1.0f);
}

// ---------- kernel 1: W -> f16, transposed to [768 n][256 k] ----------
__global__ void conv_w_kernel(const float* __restrict__ Wr,
                              const float* __restrict__ Wz,
                              const float* __restrict__ Wh,
                              half_t* __restrict__ Wt) {
  int n = blockIdx.x;          // 0..767
  int k = threadIdx.x;         // 0..255
  const float* W = (n < 256) ? Wr : ((n < 512) ? Wz : Wh);
  int j = n & 255;
  Wt[(size_t)n * DIM + k] = (half_t)W[(size_t)k * DIM + j];
}

// ---------- kernel 2: a = sigmoid(x@k1 - x@k2) per row ----------
__global__ __launch_bounds__(256) void attn_a_kernel(const float* __restrict__ inp,
                                                     const float* __restrict__ k1,
                                                     const float* __restrict__ k2,
                                                     float* __restrict__ a_arr) {
  int row  = blockIdx.x * 4 + (threadIdx.x >> 6);
  int lane = threadIdx.x & 63;
  const float4* x4 = (const float4*)(inp + (size_t)row * DIM);
  float4 xv  = x4[lane];
  float4 k1v = ((const float4*)k1)[lane];
  float4 k2v = ((const float4*)k2)[lane];
  float e1 = xv.x * k1v.x + xv.y * k1v.y + xv.z * k1v.z + xv.w * k1v.w;
  float e2 = xv.x * k2v.x + xv.y * k2v.y + xv.z * k2v.z + xv.w * k2v.w;
#pragma unroll
  for (int off = 32; off >= 1; off >>= 1) {
    e1 += __shfl_xor(e1, off);
    e2 += __shfl_xor(e2, off);
  }
  if (lane == 0) a_arr[row] = 1.0f / (1.0f + __expf(e2 - e1));
}

// ---------- kernel 3: P = X @ [Wr|Wz|Wh]  (MFMA f16, f32 acc, store f16) ----------
__global__ __launch_bounds__(256) void gemm_p_kernel(const float* __restrict__ X,
                                                     const half_t* __restrict__ Wt,
                                                     half_t* __restrict__ P) {
  __shared__ __align__(16) half_t As[128][32];
  __shared__ __align__(16) half_t Bs[128][32];
  const int tid  = threadIdx.x;
  const int bm   = blockIdx.x * 128;
  const int bn   = blockIdx.y * 128;
  const int lane = tid & 63;
  const int wave = tid >> 6;
  const int wm   = (wave >> 1) * 64;
  const int wn   = (wave & 1) * 64;
  const int quad = lane >> 4;
  const int l15  = lane & 15;
  const int r0   = tid >> 2;
  const int kc   = (tid & 3) * 8;

  floatx4 acc[4][4] = {};

  for (int k0 = 0; k0 < DIM; k0 += 32) {
#pragma unroll
    for (int hh = 0; hh < 2; ++hh) {
      int r = r0 + hh * 64;
      const float* asrc = X + (size_t)(bm + r) * DIM + k0 + kc;
      float4 f0 = *(const float4*)(asrc);
      float4 f1 = *(const float4*)(asrc + 4);
      half8_t av;
      av[0] = (half_t)f0.x; av[1] = (half_t)f0.y; av[2] = (half_t)f0.z; av[3] = (half_t)f0.w;
      av[4] = (half_t)f1.x; av[5] = (half_t)f1.y; av[6] = (half_t)f1.z; av[7] = (half_t)f1.w;
      *(half8_t*)(&As[r][kc]) = av;
      *(half8_t*)(&Bs[r][kc]) = *(const half8_t*)(Wt + (size_t)(bn + r) * DIM + k0 + kc);
    }
    __syncthreads();
    half8_t af[4], bf[4];
#pragma unroll
    for (int mi = 0; mi < 4; ++mi)
      af[mi] = *(const half8_t*)(&As[wm + mi * 16 + l15][quad * 8]);
#pragma unroll
    for (int ni = 0; ni < 4; ++ni)
      bf[ni] = *(const half8_t*)(&Bs[wn + ni * 16 + l15][quad * 8]);
#pragma unroll
    for (int mi = 0; mi < 4; ++mi)
#pragma unroll
      for (int ni = 0; ni < 4; ++ni)
        acc[mi][ni] = __builtin_amdgcn_mfma_f32_16x16x32_f16(af[mi], bf[ni], acc[mi][ni], 0, 0, 0);
    __syncthreads();
  }
#pragma unroll
  for (int mi = 0; mi < 4; ++mi)
#pragma unroll
    for (int ni = 0; ni < 4; ++ni) {
      int col = bn + wn + ni * 16 + l15;
#pragma unroll
      for (int rr = 0; rr < 4; ++rr) {
        int row = bm + wm + mi * 16 + quad * 4 + rr;
        P[(size_t)row * 768 + col] = (half_t)acc[mi][ni][rr];
      }
    }
}

// ---------- kernel 4: recurrence, 1024 threads, k-split 4, NO-SPILL by construction ----------
// thread (q,j): q = tid>>8 in [0,4), j = tid&255; K-window = [q*64, q*64+64).
// Per-thread U = 3 gates x 8 u32x4 = 96 u32; total demand ~116 <= the forced
// 128-reg cap of __launch_bounds__(1024,1) (131072/1024). R2/R4/R5 were
// L1-BW-bound reloading ~90 spilled u32/thread/step from scratch (~184 KB/step/CU
// at 64 B/cyc ~= 2900 cyc = the whole measured step time); this shape cannot spill.
__global__ __launch_bounds__(1024, 1) void recur_kernel(
    const half_t* __restrict__ P,     // [32768, 768] f16 (xWr | xWz | xWh)
    const float* __restrict__ a_arr,  // [32768]
    const int* __restrict__ cidx,     // [32768]
    const float* __restrict__ Ur, const float* __restrict__ Uz, const float* __restrict__ Uh,
    const float* __restrict__ br, const float* __restrict__ bz, const float* __restrict__ bh,
    float* __restrict__ out) {        // [32768, 256] f32
  const int tid  = threadIdx.x;
  const int j    = tid & 255;
  const int q    = tid >> 8;          // 0..3
  const int koff = q * 64;            // half-element offset of this thread's K-window

  __shared__ __align__(16) half_t hist[SEQ_L][128];   // 128 KB
  __shared__ __align__(16) half_t mth[DIM];           // 512 B
  __shared__ __align__(16) floatx4 part[3][DIM];      // 12 KB: partials from q=1,2,3
  __shared__ __align__(16) float ring[16][DIM];       // 16 KB: out staging ring

  // ---- register-resident U window (packed f16 pairs): 24 u32x4 ----
  u32x4 ur4[8], uz4[8], uh4[8];
#pragma unroll
  for (int c8 = 0; c8 < 8; ++c8) {
#pragma unroll
    for (int t = 0; t < 4; ++t) {
      const int k = koff + c8 * 8 + t * 2;
      half2_t tr, tz, th;
      tr[0] = (half_t)Ur[(size_t)(k + 0) * DIM + j];
      tr[1] = (half_t)Ur[(size_t)(k + 1) * DIM + j];
      tz[0] = (half_t)Uz[(size_t)(k + 0) * DIM + j];
      tz[1] = (half_t)Uz[(size_t)(k + 1) * DIM + j];
      th[0] = (half_t)Uh[(size_t)(k + 0) * DIM + j];
      th[1] = (half_t)Uh[(size_t)(k + 1) * DIM + j];
      ur4[c8][t] = __builtin_bit_cast(uint32_t, tr);
      uz4[c8][t] = __builtin_bit_cast(uint32_t, tz);
      uh4[c8][t] = __builtin_bit_cast(uint32_t, th);
    }
  }
  const float brj = br[j], bzj = bz[j], bhj = bh[j];

  // step 0 has mt == 0 (h0 = 0, c0 = 0)
  if (tid < 128) ((uint32_t*)mth)[tid] = 0u;
  __syncthreads();

  float h   = 0.0f;   // q==0 thread j: h[j]
  float mtj = 0.0f;   // q==0 thread j: current step's mt[j] (f32)
  const int base = blockIdx.x * SEQ_L;

  // ---- prefetch state for step 0 ----
  float pr_c = 0.f, pz_c = 0.f, ph_c = 0.f;
  if (q == 0) {
    const half_t* prow = P + (size_t)base * 768;
    pr_c = (float)prow[j];
    pz_c = (float)prow[DIM + j];
    ph_c = (float)prow[2 * DIM + j];
  }
  float a_n = a_arr[base + 1];
  int   c_n = cidx[base + 1];

  for (int i = 0; i < SEQ_L; ++i) {
    // ---- next-step loads; consumed a full step later ----
    float pr_x = 0.f, pz_x = 0.f, ph_x = 0.f;
    const int ip1 = (i + 1 < SEQ_L) ? (i + 1) : i;
    if (q == 0) {
      const half_t* prow = P + (size_t)(base + ip1) * 768;
      pr_x = (float)prow[j];
      pz_x = (float)prow[DIM + j];
      ph_x = (float)prow[2 * DIM + j];
    }
    const int ip2 = (i + 2 < SEQ_L) ? (i + 2) : (SEQ_L - 1);
    const float a_x = a_arr[base + ip2];
    const int   c_x = cidx[base + ip2];

    // ---- partial dots over this thread's 64-half K-window ----
    float accr = 0.0f, accz = 0.0f, acch = 0.0f;
    const u32x4* mq = (const u32x4*)(mth + koff);
#pragma unroll
    for (int c8 = 0; c8 < 8; ++c8) {
      u32x4 m4 = mq[c8];                // ds_read_b128, 64-way broadcast (free)
      accr = fdot2f(m4.x, ur4[c8][0], accr);
      accz = fdot2f(m4.x, uz4[c8][0], accz);
      acch = fdot2f(m4.x, uh4[c8][0], acch);
      accr = fdot2f(m4.y, ur4[c8][1], accr);
      accz = fdot2f(m4.y, uz4[c8][1], accz);
      acch = fdot2f(m4.y, uh4[c8][1], acch);
      accr = fdot2f(m4.z, ur4[c8][2], accr);
      accz = fdot2f(m4.z, uz4[c8][2], accz);
      acch = fdot2f(m4.z, uh4[c8][2], acch);
      accr = fdot2f(m4.w, ur4[c8][3], accr);
      accz = fdot2f(m4.w, uz4[c8][3], accz);
      acch = fdot2f(m4.w, uh4[c8][3], acch);
    }
    if (q > 0) {
      floatx4 p;
      p[0] = accr; p[1] = accz; p[2] = acch; p[3] = 0.0f;
      part[q - 1][j] = p;               // one ds_write_b128
    }
    __syncthreads();   // B1: partials visible; mth(i) reads complete

    if (q == 0) {
      floatx4 p1 = part[0][j];
      floatx4 p2 = part[1][j];
      floatx4 p3 = part[2][j];
      accr += p1[0] + p2[0] + p3[0];
      accz += p1[1] + p2[1] + p3[1];
      acch += p1[2] + p2[2] + p3[2];
      const float rg = sigmoidf_fast(pr_c + brj + accr);
      const float zg = sigmoidf_fast(pz_c + bzj + accz);
      const float hb = tanhf_fast(ph_c + bhj + rg * acch);
      h = (1.0f - zg) * mtj + zg * hb;
      ring[i & 15][j] = h;              // LDS staging
      if (j >= 128) hist[i][j - 128] = (half_t)h;
      float mtn;
      if (j < 128) {
        mtn = a_n * h;
      } else {
        float coref = 0.0f;
        if (c_n > 0)   // uniform branch
          coref = (c_n - 1 == i) ? h : (float)hist[c_n - 1][j - 128];
        mtn = (1.0f - a_n) * coref;
      }
      mtj = mtn;
      mth[j] = (half_t)mtn;
    } else if (q == 1) {
      // flush 8 completed ring rows every 8 steps (slots disjoint from row i's)
      if ((i & 7) == 0 && i > 0) {
#pragma unroll
        for (int rr = 0; rr < 8; ++rr) {
          const int row = i - 8 + rr;
          out[(size_t)(base + row) * DIM + j] = ring[row & 15][j];
        }
      }
    }
    // rotate prefetch registers
    pr_c = pr_x; pz_c = pz_x; ph_c = ph_x;
    a_n = a_x;   c_n = c_x;
    __syncthreads();   // B2: mth(i+1) + hist(i) visible before next dot phase
  }

  // tail: rows 504..511 still in the ring (last flush at i=504 covered 496..503)
#pragma unroll
  for (int rr = 0; rr < 2; ++rr) {
    const int idx = rr * 1024 + tid;    // 0..2047
    const int row = 504 + (idx >> 8);
    const int col = idx & 255;
    out[(size_t)(base + row) * DIM + col] = ring[row & 15][col];
  }
}

// ---------- launcher ----------
extern "C" void kernel_launch(void* const* d_in, const int* in_sizes, int n_in,
                              void* d_out, int out_size, void* d_ws, size_t ws_size,
                              hipStream_t stream) {
  const float* inp = (const float*)d_in[0];
  const int*   ci  = (const int*)d_in[1];
  const float* Wr  = (const float*)d_in[2];
  const float* br  = (const float*)d_in[3];
  const float* Ur  = (const float*)d_in[4];
  const float* Wz  = (const float*)d_in[5];
  const float* bz  = (const float*)d_in[6];
  const float* Uz  = (const float*)d_in[7];
  const float* Wh  = (const float*)d_in[8];
  const float* bh  = (const float*)d_in[9];
  const float* Uh  = (const float*)d_in[10];
  const float* k1  = (const float*)d_in[11];
  const float* k2  = (const float*)d_in[12];
  float* out = (float*)d_out;

  char* ws = (char*)d_ws;
  // ws carve: Wt [768*256 f16] | P [32768*768 f16] | a [32768 f32]
  half_t* Wt    = (half_t*)ws;
  half_t* P     = (half_t*)(ws + 393216);
  float*  a_arr = (float*)(ws + 393216 + 50331648);

  conv_w_kernel<<<dim3(768), dim3(256), 0, stream>>>(Wr, Wz, Wh, Wt);
  attn_a_kernel<<<dim3(NTOT / 4), dim3(256), 0, stream>>>(inp, k1, k2, a_arr);
  gemm_p_kernel<<<dim3(NTOT / 128, 6), dim3(256), 0, stream>>>(inp, Wt, P);
  recur_kernel<<<dim3(NBATCH), dim3(1024), 0, stream>>>(P, a_arr, ci, Ur, Uz, Uh,
                                                        br, bz, bh, out);
}

// Round 8
// 737.493 us; speedup vs baseline: 2.2349x; 2.2349x over previous
//
#include <hip/hip_runtime.h>
#include <stdint.h>
#include <stddef.h>

typedef _Float16 half_t;
typedef _Float16 half2_t __attribute__((ext_vector_type(2)));
typedef _Float16 half8_t __attribute__((ext_vector_type(8)));
typedef float    floatx4 __attribute__((ext_vector_type(4)));
typedef uint32_t u32x4   __attribute__((ext_vector_type(4)));
typedef int      intx4   __attribute__((ext_vector_type(4)));

#define SEQ_L 512
#define NBATCH 64
#define DIM 256
#define NTOT (NBATCH * SEQ_L)   // 32768 rows

// ---------- helpers ----------
__device__ __forceinline__ int dot4i8(uint32_t a, uint32_t b, int c) {
#if defined(__has_builtin)
#if __has_builtin(__builtin_amdgcn_sdot4)
  return __builtin_amdgcn_sdot4((int)a, (int)b, c, false);
#else
  int s = c;
  s += (int)(int8_t)(a)       * (int)(int8_t)(b);
  s += (int)(int8_t)(a >> 8)  * (int)(int8_t)(b >> 8);
  s += (int)(int8_t)(a >> 16) * (int)(int8_t)(b >> 16);
  s += (int)(int8_t)(a >> 24) * (int)(int8_t)(b >> 24);
  return s;
#endif
#else
  int s = c;
  s += (int)(int8_t)(a)       * (int)(int8_t)(b);
  s += (int)(int8_t)(a >> 8)  * (int)(int8_t)(b >> 8);
  s += (int)(int8_t)(a >> 16) * (int)(int8_t)(b >> 16);
  s += (int)(int8_t)(a >> 24) * (int)(int8_t)(b >> 24);
  return s;
#endif
}

__device__ __forceinline__ float sigmoidf_fast(float x) {
  return 1.0f / (1.0f + __expf(-x));
}
__device__ __forceinline__ float tanhf_fast(float x) {
  float e = __expf(2.0f * x);
  return 1.0f - 2.0f / (e + 1.0f);
}

// ---------- kernel 1: W -> f16, transposed to [768 n][256 k] ----------
__global__ void conv_w_kernel(const float* __restrict__ Wr,
                              const float* __restrict__ Wz,
                              const float* __restrict__ Wh,
                              half_t* __restrict__ Wt) {
  int n = blockIdx.x;          // 0..767
  int k = threadIdx.x;         // 0..255
  const float* W = (n < 256) ? Wr : ((n < 512) ? Wz : Wh);
  int j = n & 255;
  Wt[(size_t)n * DIM + k] = (half_t)W[(size_t)k * DIM + j];
}

// ---------- kernel 2: a = sigmoid(x@k1 - x@k2) per row ----------
__global__ __launch_bounds__(256) void attn_a_kernel(const float* __restrict__ inp,
                                                     const float* __restrict__ k1,
                                                     const float* __restrict__ k2,
                                                     float* __restrict__ a_arr) {
  int row  = blockIdx.x * 4 + (threadIdx.x >> 6);
  int lane = threadIdx.x & 63;
  const float4* x4 = (const float4*)(inp + (size_t)row * DIM);
  float4 xv  = x4[lane];
  float4 k1v = ((const float4*)k1)[lane];
  float4 k2v = ((const float4*)k2)[lane];
  float e1 = xv.x * k1v.x + xv.y * k1v.y + xv.z * k1v.z + xv.w * k1v.w;
  float e2 = xv.x * k2v.x + xv.y * k2v.y + xv.z * k2v.z + xv.w * k2v.w;
#pragma unroll
  for (int off = 32; off >= 1; off >>= 1) {
    e1 += __shfl_xor(e1, off);
    e2 += __shfl_xor(e2, off);
  }
  if (lane == 0) a_arr[row] = 1.0f / (1.0f + __expf(e2 - e1));
}

// ---------- kernel 2b: per-(gate,col) |U| max -> scale = max/127 ----------
__global__ __launch_bounds__(256) void uscale_kernel(const float* __restrict__ Ur,
                                                     const float* __restrict__ Uz,
                                                     const float* __restrict__ Uh,
                                                     float* __restrict__ su) {
  const int g = blockIdx.x;    // 0..2
  const int j = threadIdx.x;   // 0..255
  const float* U = (g == 0) ? Ur : ((g == 1) ? Uz : Uh);
  float m = 0.0f;
  for (int k = 0; k < DIM; ++k) m = fmaxf(m, fabsf(U[(size_t)k * DIM + j]));
  su[g * DIM + j] = fmaxf(m, 1e-30f) * (1.0f / 127.0f);
}

// ---------- kernel 2c: pack U -> i8 quads, layout Ui8[g][quad=k/4][j] ----------
__global__ __launch_bounds__(256) void upack_kernel(const float* __restrict__ Ur,
                                                    const float* __restrict__ Uz,
                                                    const float* __restrict__ Uh,
                                                    const float* __restrict__ su,
                                                    uint32_t* __restrict__ Ui8) {
  const int g = blockIdx.x;    // 0..2
  const int j = threadIdx.x;   // 0..255
  const float* U = (g == 0) ? Ur : ((g == 1) ? Uz : Uh);
  const float r = 1.0f / su[g * DIM + j];   // = 127/max
  for (int q = 0; q < 64; ++q) {
    uint32_t w = 0;
#pragma unroll
    for (int t = 0; t < 4; ++t) {
      float v = U[(size_t)(q * 4 + t) * DIM + j] * r;
      int mi = __float2int_rn(v);
      mi = mi < -127 ? -127 : (mi > 127 ? 127 : mi);
      w |= ((uint32_t)(mi & 0xFF)) << (8 * t);
    }
    Ui8[((size_t)g * 64 + q) * DIM + j] = w;
  }
}

// ---------- kernel 3: P = X @ [Wr|Wz|Wh]  (MFMA f16, f32 acc, store f16) ----------
__global__ __launch_bounds__(256) void gemm_p_kernel(const float* __restrict__ X,
                                                     const half_t* __restrict__ Wt,
                                                     half_t* __restrict__ P) {
  __shared__ __align__(16) half_t As[128][32];
  __shared__ __align__(16) half_t Bs[128][32];
  const int tid  = threadIdx.x;
  const int bm   = blockIdx.x * 128;
  const int bn   = blockIdx.y * 128;
  const int lane = tid & 63;
  const int wave = tid >> 6;
  const int wm   = (wave >> 1) * 64;
  const int wn   = (wave & 1) * 64;
  const int quad = lane >> 4;
  const int l15  = lane & 15;
  const int r0   = tid >> 2;
  const int kc   = (tid & 3) * 8;

  floatx4 acc[4][4] = {};

  for (int k0 = 0; k0 < DIM; k0 += 32) {
#pragma unroll
    for (int hh = 0; hh < 2; ++hh) {
      int r = r0 + hh * 64;
      const float* asrc = X + (size_t)(bm + r) * DIM + k0 + kc;
      float4 f0 = *(const float4*)(asrc);
      float4 f1 = *(const float4*)(asrc + 4);
      half8_t av;
      av[0] = (half_t)f0.x; av[1] = (half_t)f0.y; av[2] = (half_t)f0.z; av[3] = (half_t)f0.w;
      av[4] = (half_t)f1.x; av[5] = (half_t)f1.y; av[6] = (half_t)f1.z; av[7] = (half_t)f1.w;
      *(half8_t*)(&As[r][kc]) = av;
      *(half8_t*)(&Bs[r][kc]) = *(const half8_t*)(Wt + (size_t)(bn + r) * DIM + k0 + kc);
    }
    __syncthreads();
    half8_t af[4], bf[4];
#pragma unroll
    for (int mi = 0; mi < 4; ++mi)
      af[mi] = *(const half8_t*)(&As[wm + mi * 16 + l15][quad * 8]);
#pragma unroll
    for (int ni = 0; ni < 4; ++ni)
      bf[ni] = *(const half8_t*)(&Bs[wn + ni * 16 + l15][quad * 8]);
#pragma unroll
    for (int mi = 0; mi < 4; ++mi)
#pragma unroll
      for (int ni = 0; ni < 4; ++ni)
        acc[mi][ni] = __builtin_amdgcn_mfma_f32_16x16x32_f16(af[mi], bf[ni], acc[mi][ni], 0, 0, 0);
    __syncthreads();
  }
#pragma unroll
  for (int mi = 0; mi < 4; ++mi)
#pragma unroll
    for (int ni = 0; ni < 4; ++ni) {
      int col = bn + wn + ni * 16 + l15;
#pragma unroll
      for (int rr = 0; rr < 4; ++rr) {
        int row = bm + wm + mi * 16 + quad * 4 + rr;
        P[(size_t)row * 768 + col] = (half_t)acc[mi][ni][rr];
      }
    }
}

// ---------- kernel 4: recurrence, 512 threads, k-split 2, i8 dot4 ----------
// Per-thread U = 3 gates x 8 u32x4 = 96 u32 of packed i8 -> fits the empirical
// 128-arch-VGPR cap (65536/512) WITH working set: no AGPR copies, no scratch
// (the structural killer of all f16 variants: f16 U = 98304 u32/CU > 65536
// arch file). Recurrent state (mt, h) stays f32; quantization error enters
// only through the U-dots, damped by gate slopes.
__global__ __launch_bounds__(512, 1) void recur_kernel(
    const half_t* __restrict__ P,     // [32768, 768] f16 (xWr | xWz | xWh)
    const float* __restrict__ a_arr,  // [32768]
    const int* __restrict__ cidx,     // [32768]
    const uint32_t* __restrict__ Ui8, // [3][64][256] packed i8 quads
    const float* __restrict__ su,     // [3][256] scales (max/127)
    const float* __restrict__ br, const float* __restrict__ bz, const float* __restrict__ bh,
    float* __restrict__ out) {        // [32768, 256] f32
  const int tid  = threadIdx.x;
  const int j    = tid & 255;
  const int half = tid >> 8;          // 0 or 1
  // this thread's K-window: quads [half*32, half*32+32)

  __shared__ __align__(16) half_t  hist[SEQ_L][128];  // 128 KB
  __shared__ __align__(16) uint32_t mth8[64];         // 256 B: mt as i8[256]
  __shared__ __align__(16) intx4  part[DIM];          // 4 KB: half-1 int partials
  __shared__ __align__(16) float  ring[16][DIM];      // 16 KB: out staging ring

  // ---- register-resident U window: 24 u32x4 = 96 u32 of i8 quads ----
  u32x4 ur8[8], uz8[8], uh8[8];
#pragma unroll
  for (int c8 = 0; c8 < 8; ++c8) {
#pragma unroll
    for (int t = 0; t < 4; ++t) {
      const int quad = half * 32 + c8 * 4 + t;
      ur8[c8][t] = Ui8[((size_t)0 * 64 + quad) * DIM + j];
      uz8[c8][t] = Ui8[((size_t)1 * 64 + quad) * DIM + j];
      uh8[c8][t] = Ui8[((size_t)2 * 64 + quad) * DIM + j];
    }
  }
  // dequant factors: su already = max/127; mt scale = 1/127
  const float scr = su[0 * DIM + j] * (1.0f / 127.0f);
  const float scz = su[1 * DIM + j] * (1.0f / 127.0f);
  const float sch = su[2 * DIM + j] * (1.0f / 127.0f);
  const float brj = br[j], bzj = bz[j], bhj = bh[j];

  // step 0 has mt == 0 (h0 = 0, c0 = 0)
  if (tid < 64) mth8[tid] = 0u;
  __syncthreads();

  float h   = 0.0f;   // half-0 thread j: h[j]
  float mtj = 0.0f;   // half-0 thread j: current step's mt[j] (f32, exact)
  const int base = blockIdx.x * SEQ_L;

  // ---- prefetch state for step 0 ----
  float pr_c = 0.f, pz_c = 0.f, ph_c = 0.f;
  if (half == 0) {
    const half_t* prow = P + (size_t)base * 768;
    pr_c = (float)prow[j];
    pz_c = (float)prow[DIM + j];
    ph_c = (float)prow[2 * DIM + j];
  }
  float a_n = a_arr[base + 1];
  int   c_n = cidx[base + 1];

  for (int i = 0; i < SEQ_L; ++i) {
    // ---- next-step loads; consumed a full step later ----
    float pr_x = 0.f, pz_x = 0.f, ph_x = 0.f;
    const int ip1 = (i + 1 < SEQ_L) ? (i + 1) : i;
    if (half == 0) {
      const half_t* prow = P + (size_t)(base + ip1) * 768;
      pr_x = (float)prow[j];
      pz_x = (float)prow[DIM + j];
      ph_x = (float)prow[2 * DIM + j];
    }
    const int ip2 = (i + 2 < SEQ_L) ? (i + 2) : (SEQ_L - 1);
    const float a_x = a_arr[base + ip2];
    const int   c_x = cidx[base + ip2];

    // ---- i8 dots over this thread's 128-element K-half ----
    int ar = 0, az = 0, ah = 0;
    const u32x4* mq = (const u32x4*)(mth8 + half * 32);
#pragma unroll
    for (int c8 = 0; c8 < 8; ++c8) {
      u32x4 m4 = mq[c8];                // ds_read_b128, 64-way broadcast
      ar = dot4i8(m4.x, ur8[c8][0], ar);
      az = dot4i8(m4.x, uz8[c8][0], az);
      ah = dot4i8(m4.x, uh8[c8][0], ah);
      ar = dot4i8(m4.y, ur8[c8][1], ar);
      az = dot4i8(m4.y, uz8[c8][1], az);
      ah = dot4i8(m4.y, uh8[c8][1], ah);
      ar = dot4i8(m4.z, ur8[c8][2], ar);
      az = dot4i8(m4.z, uz8[c8][2], az);
      ah = dot4i8(m4.z, uh8[c8][2], ah);
      ar = dot4i8(m4.w, ur8[c8][3], ar);
      az = dot4i8(m4.w, uz8[c8][3], az);
      ah = dot4i8(m4.w, uh8[c8][3], ah);
    }
    if (half == 1) {
      intx4 p;
      p[0] = ar; p[1] = az; p[2] = ah; p[3] = 0;
      part[j] = p;                      // one ds_write_b128
    }
    __syncthreads();   // B1: partials visible; mth8(i) reads complete

    if (half == 0) {
      intx4 p1 = part[j];               // one ds_read_b128
      const float fr = (float)(ar + p1[0]) * scr;
      const float fz = (float)(az + p1[1]) * scz;
      const float fh = (float)(ah + p1[2]) * sch;
      const float rg = sigmoidf_fast(pr_c + brj + fr);
      const float zg = sigmoidf_fast(pz_c + bzj + fz);
      const float hb = tanhf_fast(ph_c + bhj + rg * fh);
      h = (1.0f - zg) * mtj + zg * hb;
      ring[i & 15][j] = h;              // LDS staging
      if (j >= 128) hist[i][j - 128] = (half_t)h;
      // next step's mt (f32 exact for the recurrent path)
      float mtn;
      if (j < 128) {
        mtn = a_n * h;
      } else {
        float coref = 0.0f;
        if (c_n > 0)   // uniform branch
          coref = (c_n - 1 == i) ? h : (float)hist[c_n - 1][j - 128];
        mtn = (1.0f - a_n) * coref;
      }
      mtj = mtn;
      // quantize + pack 4 lanes' bytes -> one u32 (|mt| <= 1 by induction)
      int mi = __float2int_rn(mtn * 127.0f);
      mi = mi < -127 ? -127 : (mi > 127 ? 127 : mi);
      unsigned v0 = (unsigned)mi & 0xFFu;
      unsigned v1 = (unsigned)__shfl_xor((int)v0, 1) & 0xFFu;
      unsigned pp = (j & 1) ? (v1 | (v0 << 8)) : (v0 | (v1 << 8));
      unsigned v2 = (unsigned)__shfl_xor((int)pp, 2);
      unsigned qd = (j & 2) ? ((v2 & 0xFFFFu) | (pp << 16))
                            : ((pp & 0xFFFFu) | (v2 << 16));
      if ((j & 3) == 0) mth8[j >> 2] = qd;
    } else {
      // half-1 waves: flush 8 completed ring rows every 8 steps
      if ((i & 7) == 0 && i > 0) {
#pragma unroll
        for (int rr = 0; rr < 8; ++rr) {
          const int row = i - 8 + rr;
          out[(size_t)(base + row) * DIM + j] = ring[row & 15][j];
        }
      }
    }
    // rotate prefetch registers
    pr_c = pr_x; pz_c = pz_x; ph_c = ph_x;
    a_n = a_x;   c_n = c_x;
    __syncthreads();   // B2: mth8(i+1) + hist(i) visible before next dot phase
  }

  // tail: rows 504..511 still in the ring
#pragma unroll
  for (int rr = 0; rr < 4; ++rr) {
    const int idx = rr * 512 + tid;     // 0..2047
    const int row = 504 + (idx >> 8);
    const int col = idx & 255;
    out[(size_t)(base + row) * DIM + col] = ring[row & 15][col];
  }
}

// ---------- launcher ----------
extern "C" void kernel_launch(void* const* d_in, const int* in_sizes, int n_in,
                              void* d_out, int out_size, void* d_ws, size_t ws_size,
                              hipStream_t stream) {
  const float* inp = (const float*)d_in[0];
  const int*   ci  = (const int*)d_in[1];
  const float* Wr  = (const float*)d_in[2];
  const float* br  = (const float*)d_in[3];
  const float* Ur  = (const float*)d_in[4];
  const float* Wz  = (const float*)d_in[5];
  const float* bz  = (const float*)d_in[6];
  const float* Uz  = (const float*)d_in[7];
  const float* Wh  = (const float*)d_in[8];
  const float* bh  = (const float*)d_in[9];
  const float* Uh  = (const float*)d_in[10];
  const float* k1  = (const float*)d_in[11];
  const float* k2  = (const float*)d_in[12];
  float* out = (float*)d_out;

  char* ws = (char*)d_ws;
  // ws carve: Wt f16 [768*256] | P f16 [32768*768] | a f32 [32768]
  //           | su f32 [3*256] | Ui8 u32 [3*64*256]
  half_t*   Wt    = (half_t*)ws;                               // 393216 B
  half_t*   P     = (half_t*)(ws + 393216);                    // 50331648 B
  float*    a_arr = (float*)(ws + 393216 + 50331648);          // 131072 B
  float*    su    = (float*)(ws + 50855936);                   // 3072 B
  uint32_t* Ui8   = (uint32_t*)(ws + 50859008);                // 196608 B

  conv_w_kernel<<<dim3(768), dim3(256), 0, stream>>>(Wr, Wz, Wh, Wt);
  attn_a_kernel<<<dim3(NTOT / 4), dim3(256), 0, stream>>>(inp, k1, k2, a_arr);
  uscale_kernel<<<dim3(3), dim3(256), 0, stream>>>(Ur, Uz, Uh, su);
  upack_kernel<<<dim3(3), dim3(256), 0, stream>>>(Ur, Uz, Uh, su, Ui8);
  gemm_p_kernel<<<dim3(NTOT / 128, 6), dim3(256), 0, stream>>>(inp, Wt, P);
  recur_kernel<<<dim3(NBATCH), dim3(512), 0, stream>>>(P, a_arr, ci, Ui8, su,
                                                       br, bz, bh, out);
}